// Round 10
// baseline (210.224 us; speedup 1.0000x reference)
//
#include <hip/hip_runtime.h>
#include <cstdint>
#include <cstddef>

#define N_INST 8192
#define L_DIM  384
#define D_DIM  128
#define C_CLS  5

typedef __bf16 bf16x8 __attribute__((ext_vector_type(8)));
typedef float  f32x4  __attribute__((ext_vector_type(4)));
typedef float  f32x4u __attribute__((ext_vector_type(4), aligned(4)));

typedef __attribute__((address_space(1))) void gvoid_t;
typedef __attribute__((address_space(3))) void lvoid_t;

__device__ __forceinline__ unsigned short f2bf(float f) {
  unsigned u = __float_as_uint(f);
  unsigned r = (u + 0x7FFFu + ((u >> 16) & 1u)) >> 16;  // RNE
  return (unsigned short)r;
}
__device__ __forceinline__ float bf2f(unsigned short b) {
  return __uint_as_float(((unsigned)b) << 16);
}

__device__ __forceinline__ void gload_lds16(const void* g, void* lds) {
  __builtin_amdgcn_global_load_lds(
      (gvoid_t*)(uintptr_t)g,
      (lvoid_t*)(uint32_t)(uintptr_t)lds,
      16, 0, 0);
}

// ---- prep: x -> bf16, sq[i] = sum(bf16(x_i)^2) in fp32 -------------------
__global__ __launch_bounds__(256) void prep_x_kernel(
    const float* __restrict__ x, unsigned short* __restrict__ xbf,
    float* __restrict__ sq) {
  int w = threadIdx.x >> 6, lane = threadIdx.x & 63;
  int row = blockIdx.x * 4 + w;
  const float* xr = x + (size_t)row * L_DIM;
  unsigned short* br = xbf + (size_t)row * L_DIM;
  float s = 0.f;
#pragma unroll
  for (int k = 0; k < 6; ++k) {
    float v = xr[lane + 64 * k];
    unsigned short b = f2bf(v);
    br[lane + 64 * k] = b;
    float vb = bf2f(b);
    s = fmaf(vb, vb, s);
  }
#pragma unroll
  for (int off = 32; off; off >>= 1) s += __shfl_down(s, off, 64);
  if (lane == 0) sq[row] = s;
}

// ---- prep: aW1 [384][128] -> aW1T_bf [128][384] --------------------------
__global__ __launch_bounds__(256) void prep_w_kernel(
    const float* __restrict__ aW1, unsigned short* __restrict__ w1t) {
  int idx = blockIdx.x * 256 + threadIdx.x;  // 49152 total
  int d = idx / L_DIM, l = idx - d * L_DIM;
  w1t[idx] = f2bf(aW1[(size_t)l * D_DIM + d]);
}

// ---- fused attention: logits -> exp_att + colsum (attc fused in) ---------
// Per block: 128 rows. After the GEMM, tanh values stay in registers; each
// thread reduces its 16 d-slots against aW2 into LDS partials [row][8][5];
// 128 threads finish rows: logits -> exp -> exp_att + block colsum.
__global__ __launch_bounds__(256, 2) void attn_gemm_kernel(
    const unsigned short* __restrict__ amat,   // x_bf [8192][384]
    const unsigned short* __restrict__ bmat,   // aW1T_bf [128][384]
    const float* __restrict__ bias,            // ab1 [128]
    const float* __restrict__ aW2,             // [128][5]
    const float* __restrict__ ab2,             // [5]
    float* __restrict__ exp_att,               // [8192][5]
    float* __restrict__ colsum) {              // [5]
  __shared__ alignas(16) unsigned short As[128][64];
  __shared__ alignas(16) unsigned short Bs[128][64];
  __shared__ float aW2_l[D_DIM * C_CLS];
  __shared__ float part[128][8][C_CLS];
  __shared__ float cs_l[C_CLS];

  int tid = threadIdx.x;
  int w = tid >> 6, lane = tid & 63;
  int wr = w >> 1, wc = w & 1;
  int i0 = blockIdx.x * 128;

  for (int idx = tid; idx < D_DIM * C_CLS; idx += 256) aW2_l[idx] = aW2[idx];
  if (tid < C_CLS) cs_l[tid] = 0.f;

  const unsigned short* asrc = amat + (size_t)i0 * L_DIM;
  const unsigned short* bsrc = bmat;

  f32x4 acc[4][4];
#pragma unroll
  for (int m = 0; m < 4; ++m)
#pragma unroll
    for (int n = 0; n < 4; ++n) acc[m][n] = (f32x4){0.f, 0.f, 0.f, 0.f};

  int lrow = lane & 15, lkb = lane >> 4;

  for (int kc = 0; kc < 6; ++kc) {
    int k0 = kc * 64;
#pragma unroll
    for (int c = 0; c < 4; ++c) {
      int rb = c * 32 + w * 8;
      gload_lds16(asrc + (size_t)(rb + (lane >> 3)) * L_DIM + k0 + (lane & 7) * 8,
                  &As[rb][0]);
      gload_lds16(bsrc + (size_t)(rb + (lane >> 3)) * L_DIM + k0 + (lane & 7) * 8,
                  &Bs[rb][0]);
    }
    __syncthreads();
#pragma unroll
    for (int kk = 0; kk < 64; kk += 32) {
      bf16x8 af[4], bfr[4];
#pragma unroll
      for (int m = 0; m < 4; ++m)
        af[m] = *(const bf16x8*)&As[wr * 64 + m * 16 + lrow][kk + lkb * 8];
#pragma unroll
      for (int n = 0; n < 4; ++n)
        bfr[n] = *(const bf16x8*)&Bs[wc * 64 + n * 16 + lrow][kk + lkb * 8];
#pragma unroll
      for (int m = 0; m < 4; ++m)
#pragma unroll
        for (int n = 0; n < 4; ++n)
          acc[m][n] = __builtin_amdgcn_mfma_f32_16x16x32_bf16(
              bfr[n], af[m], acc[m][n], 0, 0, 0);  // swapped operands
    }
    __syncthreads();
  }

  // tanh + per-thread partial dot with aW2 over its 16 d-slots
  int q = wc * 4 + lkb;  // contributor index 0..7 per row
#pragma unroll
  for (int m = 0; m < 4; ++m) {
    int row_l = wr * 64 + m * 16 + lrow;
    float p[C_CLS] = {0.f, 0.f, 0.f, 0.f, 0.f};
#pragma unroll
    for (int n = 0; n < 4; ++n) {
      int d0 = wc * 64 + n * 16 + lkb * 4;
#pragma unroll
      for (int r = 0; r < 4; ++r) {
        float v = tanhf(acc[m][n][r] + bias[d0 + r]);
        const float* wrow = &aW2_l[(d0 + r) * C_CLS];
#pragma unroll
        for (int c = 0; c < C_CLS; ++c) p[c] = fmaf(v, wrow[c], p[c]);
      }
    }
#pragma unroll
    for (int c = 0; c < C_CLS; ++c) part[row_l][q][c] = p[c];
  }
  __syncthreads();

  if (tid < 128) {
    int gi = i0 + tid;
    float a[C_CLS];
#pragma unroll
    for (int c = 0; c < C_CLS; ++c) a[c] = ab2[c];
#pragma unroll
    for (int qq = 0; qq < 8; ++qq)
#pragma unroll
      for (int c = 0; c < C_CLS; ++c) a[c] += part[tid][qq][c];
#pragma unroll
    for (int c = 0; c < C_CLS; ++c) {
      float e = expf(a[c]);
      exp_att[(size_t)gi * C_CLS + c] = e;
      atomicAdd(&cs_l[c], e);
    }
  }
  __syncthreads();
  if (tid < C_CLS) atomicAdd(&colsum[tid], cs_l[tid]);
}

// ---- head: dist cols j=0,1,2 for all rows (window leftovers) -------------
__global__ __launch_bounds__(256) void head_kernel(
    const unsigned short* __restrict__ xbf, const float* __restrict__ sqv,
    float* __restrict__ F) {
  int w = threadIdx.x >> 6, lane = threadIdx.x & 63;
  int i = blockIdx.x * 4 + w;
  float a0 = 0.f, a1 = 0.f, a2 = 0.f;
  if (lane < 48) {
    const unsigned short* xi = xbf + (size_t)i * L_DIM + lane * 8;
    const unsigned short* x0 = xbf + lane * 8;
    const unsigned short* x1 = xbf + L_DIM + lane * 8;
    const unsigned short* x2 = xbf + 2 * L_DIM + lane * 8;
#pragma unroll
    for (int e = 0; e < 8; ++e) {
      float v = bf2f(xi[e]);
      a0 = fmaf(v, bf2f(x0[e]), a0);
      a1 = fmaf(v, bf2f(x1[e]), a1);
      a2 = fmaf(v, bf2f(x2[e]), a2);
    }
  }
#pragma unroll
  for (int off = 32; off; off >>= 1) {
    a0 += __shfl_down(a0, off, 64);
    a1 += __shfl_down(a1, off, 64);
    a2 += __shfl_down(a2, off, 64);
  }
  if (lane == 0) {
    float si = sqv[i];
    float dots[3] = {a0, a1, a2};
#pragma unroll
    for (int j = 0; j < 3; ++j) {
      float d2 = si + sqv[j] - 2.f * dots[j];
      float dv = (d2 > 0.f) ? sqrtf(d2) : 0.f;
      if (i == j) dv = 0.f;
      F[5 + (size_t)i * N_INST + j] = dv;
    }
  }
}

// ---- dist GEMM: upper-tri grid, mirror written direct from registers -----
// dist[i][j] at F[5 + i*8192 + j]. 2080 blocks: tile (ti,tj), ti<=tj.
// Normal tile written with the R5 vector epilogue; off-diag blocks ALSO
// write the mirrored tile (j,i) directly from the same accumulators with
// scalar scatter stores (R1 vs R2 showed scatter stores cost ~nothing
// here). Halves staging reads, MFMA, barriers and block count per output
// byte vs the full grid; writes (mandatory 268 MB) unchanged.
// Inner loop identical to R5 (T2 XOR-swizzled 32 KB LDS, 2 blocks/CU+).
// acc[m][n][r] = dot(i,j): i = i0+wr*64+m*16+lrow ; j = j0+wc*64+n*16+lkb*4+r
__global__ __launch_bounds__(256, 2) void dist_kernel(
    const unsigned short* __restrict__ xbf, const float* __restrict__ sqv,
    float* __restrict__ F) {
  __shared__ alignas(16) unsigned short As[128][64];
  __shared__ alignas(16) unsigned short Bs[128][64];

  int tid = threadIdx.x;
  int w = tid >> 6, lane = tid & 63;
  int wr = w >> 1, wc = w & 1;

  // map b -> upper-tri (ti,tj): row ti has 64-ti tiles; C(t) = t*(129-t)/2
  int b = blockIdx.x;
  int ti = (int)((129.0 - sqrt(129.0 * 129.0 - 8.0 * (double)b)) * 0.5);
  while ((ti + 1) * (129 - (ti + 1)) / 2 <= b) ++ti;
  while (ti * (129 - ti) / 2 > b) --ti;
  int tj = ti + (b - ti * (129 - ti) / 2);
  int i0 = ti * 128, j0 = tj * 128;

  const unsigned short* asrc = xbf + (size_t)i0 * L_DIM;
  const unsigned short* bsrc = xbf + (size_t)j0 * L_DIM;

  f32x4 acc[4][4];
#pragma unroll
  for (int m = 0; m < 4; ++m)
#pragma unroll
    for (int n = 0; n < 4; ++n) acc[m][n] = (f32x4){0.f, 0.f, 0.f, 0.f};

  int lrow = lane & 15, lkb = lane >> 4;
  int schunk = ((lane & 7) ^ (lane >> 3)) * 8;  // pre-swizzled source chunk
  int swz = (lane & 7) << 3;                    // read-side xor

  for (int kc = 0; kc < 6; ++kc) {
    int k0 = kc * 64;
#pragma unroll
    for (int c = 0; c < 4; ++c) {
      int rb = c * 32 + w * 8;  // wave-uniform LDS base row (rb % 8 == 0)
      gload_lds16(asrc + (size_t)(rb + (lane >> 3)) * L_DIM + k0 + schunk,
                  &As[rb][0]);
      gload_lds16(bsrc + (size_t)(rb + (lane >> 3)) * L_DIM + k0 + schunk,
                  &Bs[rb][0]);
    }
    __syncthreads();
#pragma unroll
    for (int kk = 0; kk < 64; kk += 32) {
      bf16x8 af[4], bfr[4];
#pragma unroll
      for (int m = 0; m < 4; ++m)
        af[m] = *(const bf16x8*)&As[wr * 64 + m * 16 + lrow][(kk + lkb * 8) ^ swz];
#pragma unroll
      for (int n = 0; n < 4; ++n)
        bfr[n] = *(const bf16x8*)&Bs[wc * 64 + n * 16 + lrow][(kk + lkb * 8) ^ swz];
#pragma unroll
      for (int m = 0; m < 4; ++m)
#pragma unroll
        for (int n = 0; n < 4; ++n)
          acc[m][n] = __builtin_amdgcn_mfma_f32_16x16x32_bf16(
              bfr[n], af[m], acc[m][n], 0, 0, 0);  // swapped operands
    }
    __syncthreads();
  }

  bool mirror = (ti != tj);
#pragma unroll
  for (int m = 0; m < 4; ++m) {
    int gi = i0 + wr * 64 + m * 16 + lrow;
    float si = sqv[gi];
    float* orow = F + 5 + (size_t)gi * N_INST;
#pragma unroll
    for (int n = 0; n < 4; ++n) {
      int gjb = j0 + wc * 64 + n * 16 + lkb * 4;
      f32x4 sj = *(const f32x4*)&sqv[gjb];
      f32x4u o;
#pragma unroll
      for (int r = 0; r < 4; ++r) {
        float d2 = si + sj[r] - 2.f * acc[m][n][r];
        float dv = (d2 > 0.f) ? sqrtf(d2) : 0.f;
        if (gi == gjb + r) dv = 0.f;
        o[r] = dv;
      }
      *(f32x4u*)&orow[gjb] = o;
      if (mirror) {
#pragma unroll
        for (int r = 0; r < 4; ++r)
          F[5 + (size_t)(gjb + r) * N_INST + gi] = o[r];
      }
    }
  }
}

// ---- bagU[c][l] = sum_i exp_att[i][c] * x[i][l] --------------------------
__global__ __launch_bounds__(256) void bag_kernel(
    const float* __restrict__ x, const float* __restrict__ exp_att,
    float* __restrict__ bagU) {
  int t = threadIdx.x;
  int rbase = blockIdx.x * 32;
  float acc0[C_CLS] = {0, 0, 0, 0, 0}, acc1[C_CLS] = {0, 0, 0, 0, 0};
  int l0 = t, l1 = t + 256;  // l1 valid when t < 128
  for (int i = rbase; i < rbase + 32; ++i) {
    const float* xr = x + (size_t)i * L_DIM;
    float e[C_CLS];
#pragma unroll
    for (int c = 0; c < C_CLS; ++c) e[c] = exp_att[(size_t)i * C_CLS + c];
    float x0 = xr[l0];
#pragma unroll
    for (int c = 0; c < C_CLS; ++c) acc0[c] = fmaf(e[c], x0, acc0[c]);
    if (t < 128) {
      float x1 = xr[l1];
#pragma unroll
      for (int c = 0; c < C_CLS; ++c) acc1[c] = fmaf(e[c], x1, acc1[c]);
    }
  }
#pragma unroll
  for (int c = 0; c < C_CLS; ++c) atomicAdd(&bagU[c * L_DIM + l0], acc0[c]);
  if (t < 128)
#pragma unroll
    for (int c = 0; c < C_CLS; ++c) atomicAdd(&bagU[c * L_DIM + l1], acc1[c]);
}

// ---- final: normalize bag, per-class MLP head, write pred[0..4] ----------
__global__ __launch_bounds__(256) void final_kernel(
    const float* __restrict__ bagU, const float* __restrict__ colsum,
    const float* __restrict__ cW1, const float* __restrict__ cb1,
    const float* __restrict__ cW2, const float* __restrict__ cb2,
    float* __restrict__ out) {
  __shared__ float bag_s[C_CLS * L_DIM];
  __shared__ float h_s[C_CLS * 64];
  int t = threadIdx.x;
  for (int idx = t; idx < C_CLS * L_DIM; idx += 256) {
    int c = idx / L_DIM;
    bag_s[idx] = bagU[idx] / colsum[c];
  }
  __syncthreads();
  for (int idx = t; idx < C_CLS * 64; idx += 256) {
    int c = idx >> 6, hh = idx & 63;
    float acc = cb1[idx];
    for (int l = 0; l < L_DIM; ++l)
      acc = fmaf(bag_s[c * L_DIM + l], cW1[(size_t)(c * L_DIM + l) * 64 + hh], acc);
    h_s[idx] = fmaxf(acc, 0.f) * cW2[idx];
  }
  __syncthreads();
  if (t < C_CLS) {
    float p = cb2[t];
    for (int hh = 0; hh < 64; ++hh) p += h_s[t * 64 + hh];
    out[t] = p;
  }
}

extern "C" void kernel_launch(void* const* d_in, const int* in_sizes, int n_in,
                              void* d_out, int out_size, void* d_ws,
                              size_t ws_size, hipStream_t stream) {
  const float* x   = (const float*)d_in[0];
  const float* aW1 = (const float*)d_in[1];
  const float* ab1 = (const float*)d_in[2];
  const float* aW2 = (const float*)d_in[3];
  const float* ab2 = (const float*)d_in[4];
  const float* cW1 = (const float*)d_in[5];
  const float* cb1 = (const float*)d_in[6];
  const float* cW2 = (const float*)d_in[7];
  const float* cb2 = (const float*)d_in[8];
  float* outp = (float*)d_out;

  char* ws = (char*)d_ws;
  unsigned short* xbf = (unsigned short*)(ws);              // 6,291,456
  unsigned short* w1t = (unsigned short*)(ws + 6291456);    //    98,304
  float* sq           = (float*)(ws + 6389760);             //    32,768
  float* exp_att      = (float*)(ws + 6422528);             //   163,840
  float* colsum       = (float*)(ws + 6586368);             //        64
  float* bagU         = (float*)(ws + 6586432);             //     7,680

  hipMemsetAsync(ws + 6586368, 0, 64 + C_CLS * L_DIM * 4, stream);

  prep_x_kernel<<<2048, 256, 0, stream>>>(x, xbf, sq);
  prep_w_kernel<<<192, 256, 0, stream>>>(aW1, w1t);
  attn_gemm_kernel<<<64, 256, 0, stream>>>(xbf, w1t, ab1, aW2, ab2, exp_att,
                                           colsum);
  bag_kernel<<<256, 256, 0, stream>>>(x, exp_att, bagU);
  final_kernel<<<1, 256, 0, stream>>>(bagU, colsum, cW1, cb1, cW2, cb2, outp);
  head_kernel<<<2048, 256, 0, stream>>>(xbf, sq, outp);
  dist_kernel<<<2080, 256, 0, stream>>>(xbf, sq, outp);
}

// Round 11
// 186.652 us; speedup vs baseline: 1.1263x; 1.1263x over previous
//
#include <hip/hip_runtime.h>
#include <cstdint>
#include <cstddef>

#define N_INST 8192
#define L_DIM  384
#define D_DIM  128
#define C_CLS  5

typedef __bf16 bf16x8 __attribute__((ext_vector_type(8)));
typedef float  f32x4  __attribute__((ext_vector_type(4)));
typedef float  f32x4u __attribute__((ext_vector_type(4), aligned(4)));

typedef __attribute__((address_space(1))) void gvoid_t;
typedef __attribute__((address_space(3))) void lvoid_t;

__device__ __forceinline__ unsigned short f2bf(float f) {
  unsigned u = __float_as_uint(f);
  unsigned r = (u + 0x7FFFu + ((u >> 16) & 1u)) >> 16;  // RNE
  return (unsigned short)r;
}
__device__ __forceinline__ float bf2f(unsigned short b) {
  return __uint_as_float(((unsigned)b) << 16);
}

__device__ __forceinline__ void gload_lds16(const void* g, void* lds) {
  __builtin_amdgcn_global_load_lds(
      (gvoid_t*)(uintptr_t)g,
      (lvoid_t*)(uint32_t)(uintptr_t)lds,
      16, 0, 0);
}

// ---- prep: x -> bf16, sq[i] = sum(bf16(x_i)^2) in fp32 -------------------
__global__ __launch_bounds__(256) void prep_x_kernel(
    const float* __restrict__ x, unsigned short* __restrict__ xbf,
    float* __restrict__ sq) {
  int w = threadIdx.x >> 6, lane = threadIdx.x & 63;
  int row = blockIdx.x * 4 + w;
  const float* xr = x + (size_t)row * L_DIM;
  unsigned short* br = xbf + (size_t)row * L_DIM;
  float s = 0.f;
#pragma unroll
  for (int k = 0; k < 6; ++k) {
    float v = xr[lane + 64 * k];
    unsigned short b = f2bf(v);
    br[lane + 64 * k] = b;
    float vb = bf2f(b);
    s = fmaf(vb, vb, s);
  }
#pragma unroll
  for (int off = 32; off; off >>= 1) s += __shfl_down(s, off, 64);
  if (lane == 0) sq[row] = s;
}

// ---- prep: aW1 [384][128] -> aW1T_bf [128][384] --------------------------
__global__ __launch_bounds__(256) void prep_w_kernel(
    const float* __restrict__ aW1, unsigned short* __restrict__ w1t) {
  int idx = blockIdx.x * 256 + threadIdx.x;  // 49152 total
  int d = idx / L_DIM, l = idx - d * L_DIM;
  w1t[idx] = f2bf(aW1[(size_t)l * D_DIM + d]);
}

// ---- fused attention: GEMM + tanh + logits + exp + colsum ---------------
__global__ __launch_bounds__(256, 2) void attn_gemm_kernel(
    const unsigned short* __restrict__ amat,   // x_bf [8192][384]
    const unsigned short* __restrict__ bmat,   // aW1T_bf [128][384]
    const float* __restrict__ bias,            // ab1 [128]
    const float* __restrict__ aW2,             // [128][5]
    const float* __restrict__ ab2,             // [5]
    float* __restrict__ exp_att,               // [8192][5]
    float* __restrict__ colsum) {              // [5]
  __shared__ alignas(16) unsigned short As[128][64];
  __shared__ alignas(16) unsigned short Bs[128][64];
  __shared__ float aW2_l[D_DIM * C_CLS];
  __shared__ float part[128][8][C_CLS];
  __shared__ float cs_l[C_CLS];

  int tid = threadIdx.x;
  int w = tid >> 6, lane = tid & 63;
  int wr = w >> 1, wc = w & 1;
  int i0 = blockIdx.x * 128;

  for (int idx = tid; idx < D_DIM * C_CLS; idx += 256) aW2_l[idx] = aW2[idx];
  if (tid < C_CLS) cs_l[tid] = 0.f;

  const unsigned short* asrc = amat + (size_t)i0 * L_DIM;
  const unsigned short* bsrc = bmat;

  f32x4 acc[4][4];
#pragma unroll
  for (int m = 0; m < 4; ++m)
#pragma unroll
    for (int n = 0; n < 4; ++n) acc[m][n] = (f32x4){0.f, 0.f, 0.f, 0.f};

  int lrow = lane & 15, lkb = lane >> 4;

  for (int kc = 0; kc < 6; ++kc) {
    int k0 = kc * 64;
#pragma unroll
    for (int c = 0; c < 4; ++c) {
      int rb = c * 32 + w * 8;
      gload_lds16(asrc + (size_t)(rb + (lane >> 3)) * L_DIM + k0 + (lane & 7) * 8,
                  &As[rb][0]);
      gload_lds16(bsrc + (size_t)(rb + (lane >> 3)) * L_DIM + k0 + (lane & 7) * 8,
                  &Bs[rb][0]);
    }
    __syncthreads();
#pragma unroll
    for (int kk = 0; kk < 64; kk += 32) {
      bf16x8 af[4], bfr[4];
#pragma unroll
      for (int m = 0; m < 4; ++m)
        af[m] = *(const bf16x8*)&As[wr * 64 + m * 16 + lrow][kk + lkb * 8];
#pragma unroll
      for (int n = 0; n < 4; ++n)
        bfr[n] = *(const bf16x8*)&Bs[wc * 64 + n * 16 + lrow][kk + lkb * 8];
#pragma unroll
      for (int m = 0; m < 4; ++m)
#pragma unroll
        for (int n = 0; n < 4; ++n)
          acc[m][n] = __builtin_amdgcn_mfma_f32_16x16x32_bf16(
              bfr[n], af[m], acc[m][n], 0, 0, 0);  // swapped operands
    }
    __syncthreads();
  }

  int q = wc * 4 + lkb;  // contributor index 0..7 per row
#pragma unroll
  for (int m = 0; m < 4; ++m) {
    int row_l = wr * 64 + m * 16 + lrow;
    float p[C_CLS] = {0.f, 0.f, 0.f, 0.f, 0.f};
#pragma unroll
    for (int n = 0; n < 4; ++n) {
      int d0 = wc * 64 + n * 16 + lkb * 4;
#pragma unroll
      for (int r = 0; r < 4; ++r) {
        float v = tanhf(acc[m][n][r] + bias[d0 + r]);
        const float* wrow = &aW2_l[(d0 + r) * C_CLS];
#pragma unroll
        for (int c = 0; c < C_CLS; ++c) p[c] = fmaf(v, wrow[c], p[c]);
      }
    }
#pragma unroll
    for (int c = 0; c < C_CLS; ++c) part[row_l][q][c] = p[c];
  }
  __syncthreads();

  if (tid < 128) {
    int gi = i0 + tid;
    float a[C_CLS];
#pragma unroll
    for (int c = 0; c < C_CLS; ++c) a[c] = ab2[c];
#pragma unroll
    for (int qq = 0; qq < 8; ++qq)
#pragma unroll
      for (int c = 0; c < C_CLS; ++c) a[c] += part[tid][qq][c];
#pragma unroll
    for (int c = 0; c < C_CLS; ++c) {
      float e = expf(a[c]);
      exp_att[(size_t)gi * C_CLS + c] = e;
      atomicAdd(&cs_l[c], e);
    }
  }
  __syncthreads();
  if (tid < C_CLS) atomicAdd(&colsum[tid], cs_l[tid]);
}

// ---- head: dist cols j in [0,27) via MFMA (the pre-window columns) -------
// 64 blocks x 128 rows. Each wave: 32 rows x 32 cols, acc[2][2]; store j<27.
__global__ __launch_bounds__(256) void head_kernel(
    const unsigned short* __restrict__ xbf, const float* __restrict__ sqv,
    float* __restrict__ F) {
  int tid = threadIdx.x;
  int w = tid >> 6, lane = tid & 63;
  int lrow = lane & 15, lkb = lane >> 4;
  int rowb = blockIdx.x * 128 + w * 32;

  f32x4 acc[2][2];
#pragma unroll
  for (int m = 0; m < 2; ++m)
#pragma unroll
    for (int n = 0; n < 2; ++n) acc[m][n] = (f32x4){0.f, 0.f, 0.f, 0.f};

  for (int t = 0; t < 12; ++t) {
    bf16x8 af[2], bfr[2];
#pragma unroll
    for (int m = 0; m < 2; ++m)
      af[m] = *(const bf16x8*)(xbf + (size_t)(rowb + m * 16 + lrow) * L_DIM +
                               t * 32 + lkb * 8);
#pragma unroll
    for (int n = 0; n < 2; ++n)
      bfr[n] = *(const bf16x8*)(xbf + (size_t)(n * 16 + lrow) * L_DIM +
                                t * 32 + lkb * 8);
#pragma unroll
    for (int m = 0; m < 2; ++m)
#pragma unroll
      for (int n = 0; n < 2; ++n)
        acc[m][n] = __builtin_amdgcn_mfma_f32_16x16x32_bf16(
            bfr[n], af[m], acc[m][n], 0, 0, 0);  // swapped operands
  }

#pragma unroll
  for (int m = 0; m < 2; ++m) {
    int gi = rowb + m * 16 + lrow;
    float si = sqv[gi];
    float* orow = F + 5 + (size_t)gi * N_INST;
#pragma unroll
    for (int n = 0; n < 2; ++n) {
#pragma unroll
      for (int r = 0; r < 4; ++r) {
        int j = n * 16 + lkb * 4 + r;
        if (j < 27) {
          float d2 = si + sqv[j] - 2.f * acc[m][n][r];
          float dv = (d2 > 0.f) ? sqrtf(d2) : 0.f;
          if (gi == j) dv = 0.f;
          orow[j] = dv;
        }
      }
    }
  }
}

// ---- dist GEMM: 128B-line-aligned windows (j = 27 + 128k) ----------------
// dist[i][j] at F[5 + i*8192 + j]. Byte offset of col j is 20+4j; j=27+128k
// makes every per-row 512B segment exactly [128+512k, 128+512(k+1)) — whole
// 128B lines, NO lines shared between blocks (R9's +3 shift fixed sector
// alignment but left line seams; this removes the last sharing, which is
// the measured 1.63x writeback amplification mechanism — R7: pressure
// raised it to 2.16x). Windows k=0..63 tile [27, 8219) masked at 8192;
// head_kernel covers [0,27). B rows past 8191 read mapped workspace
// garbage; their outputs map 1:1 to masked columns (never stored).
// Inner loop = R5 (T2 XOR-swizzled 32 KB LDS).
// acc[m][n][r]: i = i0+wr*64+m*16+lrow ; j = jbase+wc*64+n*16+lkb*4+r
__global__ __launch_bounds__(256, 2) void dist_kernel(
    const unsigned short* __restrict__ xbf, const float* __restrict__ sqv,
    float* __restrict__ F) {
  __shared__ alignas(16) unsigned short As[128][64];
  __shared__ alignas(16) unsigned short Bs[128][64];

  int tid = threadIdx.x;
  int w = tid >> 6, lane = tid & 63;
  int wr = w >> 1, wc = w & 1;

  int b = blockIdx.x;
  int ti = b >> 6, tj = b & 63;
  int i0 = ti * 128;
  int jbase = tj * 128 + 27;

  const unsigned short* asrc = xbf + (size_t)i0 * L_DIM;
  const unsigned short* bsrc = xbf + (size_t)jbase * L_DIM;

  f32x4 acc[4][4];
#pragma unroll
  for (int m = 0; m < 4; ++m)
#pragma unroll
    for (int n = 0; n < 4; ++n) acc[m][n] = (f32x4){0.f, 0.f, 0.f, 0.f};

  int lrow = lane & 15, lkb = lane >> 4;
  int schunk = ((lane & 7) ^ (lane >> 3)) * 8;  // pre-swizzled source chunk
  int swz = (lane & 7) << 3;                    // read-side xor

  for (int kc = 0; kc < 6; ++kc) {
    int k0 = kc * 64;
#pragma unroll
    for (int c = 0; c < 4; ++c) {
      int rb = c * 32 + w * 8;  // wave-uniform LDS base row (rb % 8 == 0)
      gload_lds16(asrc + (size_t)(rb + (lane >> 3)) * L_DIM + k0 + schunk,
                  &As[rb][0]);
      gload_lds16(bsrc + (size_t)(rb + (lane >> 3)) * L_DIM + k0 + schunk,
                  &Bs[rb][0]);
    }
    __syncthreads();
#pragma unroll
    for (int kk = 0; kk < 64; kk += 32) {
      bf16x8 af[4], bfr[4];
#pragma unroll
      for (int m = 0; m < 4; ++m)
        af[m] = *(const bf16x8*)&As[wr * 64 + m * 16 + lrow][(kk + lkb * 8) ^ swz];
#pragma unroll
      for (int n = 0; n < 4; ++n)
        bfr[n] = *(const bf16x8*)&Bs[wc * 64 + n * 16 + lrow][(kk + lkb * 8) ^ swz];
#pragma unroll
      for (int m = 0; m < 4; ++m)
#pragma unroll
        for (int n = 0; n < 4; ++n)
          acc[m][n] = __builtin_amdgcn_mfma_f32_16x16x32_bf16(
              bfr[n], af[m], acc[m][n], 0, 0, 0);  // swapped operands
    }
    __syncthreads();
  }

  // epilogue: 16B-aligned f32x4 stores; (5+gjb) % 4 == 0 since gjb%4 == 3
#pragma unroll
  for (int m = 0; m < 4; ++m) {
    int gi = i0 + wr * 64 + m * 16 + lrow;
    float si = sqv[gi];
    float* orow = F + 5 + (size_t)gi * N_INST;
#pragma unroll
    for (int n = 0; n < 4; ++n) {
      int gjb = jbase + wc * 64 + n * 16 + lkb * 4;
      f32x4u sj = *(const f32x4u*)&sqv[gjb];
      f32x4 o;
#pragma unroll
      for (int r = 0; r < 4; ++r) {
        float d2 = si + sj[r] - 2.f * acc[m][n][r];
        float dv = (d2 > 0.f) ? sqrtf(d2) : 0.f;
        if (gi == gjb + r) dv = 0.f;
        o[r] = dv;
      }
      if (gjb < N_INST - 4) {
        *(f32x4*)&orow[gjb] = o;        // aligned full vector
      } else if (gjb < N_INST) {
        orow[N_INST - 1] = o[0];        // gjb == 8191: single last column
      }                                  // gjb >= 8192: masked (tail window)
    }
  }
}

// ---- bagU[c][l] = sum_i exp_att[i][c] * x[i][l] --------------------------
__global__ __launch_bounds__(256) void bag_kernel(
    const float* __restrict__ x, const float* __restrict__ exp_att,
    float* __restrict__ bagU) {
  int t = threadIdx.x;
  int rbase = blockIdx.x * 32;
  float acc0[C_CLS] = {0, 0, 0, 0, 0}, acc1[C_CLS] = {0, 0, 0, 0, 0};
  int l0 = t, l1 = t + 256;  // l1 valid when t < 128
  for (int i = rbase; i < rbase + 32; ++i) {
    const float* xr = x + (size_t)i * L_DIM;
    float e[C_CLS];
#pragma unroll
    for (int c = 0; c < C_CLS; ++c) e[c] = exp_att[(size_t)i * C_CLS + c];
    float x0 = xr[l0];
#pragma unroll
    for (int c = 0; c < C_CLS; ++c) acc0[c] = fmaf(e[c], x0, acc0[c]);
    if (t < 128) {
      float x1 = xr[l1];
#pragma unroll
      for (int c = 0; c < C_CLS; ++c) acc1[c] = fmaf(e[c], x1, acc1[c]);
    }
  }
#pragma unroll
  for (int c = 0; c < C_CLS; ++c) atomicAdd(&bagU[c * L_DIM + l0], acc0[c]);
  if (t < 128)
#pragma unroll
    for (int c = 0; c < C_CLS; ++c) atomicAdd(&bagU[c * L_DIM + l1], acc1[c]);
}

// ---- final: normalize bag, per-class MLP head, write pred[0..4] ----------
__global__ __launch_bounds__(256) void final_kernel(
    const float* __restrict__ bagU, const float* __restrict__ colsum,
    const float* __restrict__ cW1, const float* __restrict__ cb1,
    const float* __restrict__ cW2, const float* __restrict__ cb2,
    float* __restrict__ out) {
  __shared__ float bag_s[C_CLS * L_DIM];
  __shared__ float h_s[C_CLS * 64];
  int t = threadIdx.x;
  for (int idx = t; idx < C_CLS * L_DIM; idx += 256) {
    int c = idx / L_DIM;
    bag_s[idx] = bagU[idx] / colsum[c];
  }
  __syncthreads();
  for (int idx = t; idx < C_CLS * 64; idx += 256) {
    int c = idx >> 6, hh = idx & 63;
    float acc = cb1[idx];
    for (int l = 0; l < L_DIM; ++l)
      acc = fmaf(bag_s[c * L_DIM + l], cW1[(size_t)(c * L_DIM + l) * 64 + hh], acc);
    h_s[idx] = fmaxf(acc, 0.f) * cW2[idx];
  }
  __syncthreads();
  if (t < C_CLS) {
    float p = cb2[t];
    for (int hh = 0; hh < 64; ++hh) p += h_s[t * 64 + hh];
    out[t] = p;
  }
}

extern "C" void kernel_launch(void* const* d_in, const int* in_sizes, int n_in,
                              void* d_out, int out_size, void* d_ws,
                              size_t ws_size, hipStream_t stream) {
  const float* x   = (const float*)d_in[0];
  const float* aW1 = (const float*)d_in[1];
  const float* ab1 = (const float*)d_in[2];
  const float* aW2 = (const float*)d_in[3];
  const float* ab2 = (const float*)d_in[4];
  const float* cW1 = (const float*)d_in[5];
  const float* cb1 = (const float*)d_in[6];
  const float* cW2 = (const float*)d_in[7];
  const float* cb2 = (const float*)d_in[8];
  float* outp = (float*)d_out;

  char* ws = (char*)d_ws;
  unsigned short* xbf = (unsigned short*)(ws);              // 6,291,456
  unsigned short* w1t = (unsigned short*)(ws + 6291456);    //    98,304
  float* sq           = (float*)(ws + 6389760);             //    32,768
  float* exp_att      = (float*)(ws + 6422528);             //   163,840
  float* colsum       = (float*)(ws + 6586368);             //        64
  float* bagU         = (float*)(ws + 6586432);             //     7,680

  hipMemsetAsync(ws + 6586368, 0, 64 + C_CLS * L_DIM * 4, stream);

  prep_x_kernel<<<2048, 256, 0, stream>>>(x, xbf, sq);
  prep_w_kernel<<<192, 256, 0, stream>>>(aW1, w1t);
  attn_gemm_kernel<<<64, 256, 0, stream>>>(xbf, w1t, ab1, aW2, ab2, exp_att,
                                           colsum);
  bag_kernel<<<256, 256, 0, stream>>>(x, exp_att, bagU);
  final_kernel<<<1, 256, 0, stream>>>(bagU, colsum, cW1, cb1, cW2, cb2, outp);
  head_kernel<<<64, 256, 0, stream>>>(xbf, sq, outp);
  dist_kernel<<<4096, 256, 0, stream>>>(xbf, sq, outp);
}

// Round 12
// 186.077 us; speedup vs baseline: 1.1298x; 1.0031x over previous
//
#include <hip/hip_runtime.h>
#include <cstdint>
#include <cstddef>

#define N_INST 8192
#define L_DIM  384
#define D_DIM  128
#define C_CLS  5

typedef __bf16 bf16x8 __attribute__((ext_vector_type(8)));
typedef float  f32x4  __attribute__((ext_vector_type(4)));
typedef float  f32x4u __attribute__((ext_vector_type(4), aligned(4)));

typedef __attribute__((address_space(1))) void gvoid_t;
typedef __attribute__((address_space(3))) void lvoid_t;

__device__ __forceinline__ unsigned short f2bf(float f) {
  unsigned u = __float_as_uint(f);
  unsigned r = (u + 0x7FFFu + ((u >> 16) & 1u)) >> 16;  // RNE
  return (unsigned short)r;
}
__device__ __forceinline__ float bf2f(unsigned short b) {
  return __uint_as_float(((unsigned)b) << 16);
}

__device__ __forceinline__ void gload_lds16(const void* g, void* lds) {
  __builtin_amdgcn_global_load_lds(
      (gvoid_t*)(uintptr_t)g,
      (lvoid_t*)(uint32_t)(uintptr_t)lds,
      16, 0, 0);
}

// ---- prep: x -> bf16, sq[i] = sum(bf16(x_i)^2) in fp32 -------------------
__global__ __launch_bounds__(256) void prep_x_kernel(
    const float* __restrict__ x, unsigned short* __restrict__ xbf,
    float* __restrict__ sq) {
  int w = threadIdx.x >> 6, lane = threadIdx.x & 63;
  int row = blockIdx.x * 4 + w;
  const float* xr = x + (size_t)row * L_DIM;
  unsigned short* br = xbf + (size_t)row * L_DIM;
  float s = 0.f;
#pragma unroll
  for (int k = 0; k < 6; ++k) {
    float v = xr[lane + 64 * k];
    unsigned short b = f2bf(v);
    br[lane + 64 * k] = b;
    float vb = bf2f(b);
    s = fmaf(vb, vb, s);
  }
#pragma unroll
  for (int off = 32; off; off >>= 1) s += __shfl_down(s, off, 64);
  if (lane == 0) sq[row] = s;
}

// ---- prep: aW1 [384][128] -> aW1T_bf [128][384] --------------------------
__global__ __launch_bounds__(256) void prep_w_kernel(
    const float* __restrict__ aW1, unsigned short* __restrict__ w1t) {
  int idx = blockIdx.x * 256 + threadIdx.x;  // 49152 total
  int d = idx / L_DIM, l = idx - d * L_DIM;
  w1t[idx] = f2bf(aW1[(size_t)l * D_DIM + d]);
}

// ---- fused attention: GEMM + tanh + logits + exp + colsum ---------------
__global__ __launch_bounds__(256, 2) void attn_gemm_kernel(
    const unsigned short* __restrict__ amat,   // x_bf [8192][384]
    const unsigned short* __restrict__ bmat,   // aW1T_bf [128][384]
    const float* __restrict__ bias,            // ab1 [128]
    const float* __restrict__ aW2,             // [128][5]
    const float* __restrict__ ab2,             // [5]
    float* __restrict__ exp_att,               // [8192][5]
    float* __restrict__ colsum) {              // [5]
  __shared__ alignas(16) unsigned short As[128][64];
  __shared__ alignas(16) unsigned short Bs[128][64];
  __shared__ float aW2_l[D_DIM * C_CLS];
  __shared__ float part[128][8][C_CLS];
  __shared__ float cs_l[C_CLS];

  int tid = threadIdx.x;
  int w = tid >> 6, lane = tid & 63;
  int wr = w >> 1, wc = w & 1;
  int i0 = blockIdx.x * 128;

  for (int idx = tid; idx < D_DIM * C_CLS; idx += 256) aW2_l[idx] = aW2[idx];
  if (tid < C_CLS) cs_l[tid] = 0.f;

  const unsigned short* asrc = amat + (size_t)i0 * L_DIM;
  const unsigned short* bsrc = bmat;

  f32x4 acc[4][4];
#pragma unroll
  for (int m = 0; m < 4; ++m)
#pragma unroll
    for (int n = 0; n < 4; ++n) acc[m][n] = (f32x4){0.f, 0.f, 0.f, 0.f};

  int lrow = lane & 15, lkb = lane >> 4;

  for (int kc = 0; kc < 6; ++kc) {
    int k0 = kc * 64;
#pragma unroll
    for (int c = 0; c < 4; ++c) {
      int rb = c * 32 + w * 8;
      gload_lds16(asrc + (size_t)(rb + (lane >> 3)) * L_DIM + k0 + (lane & 7) * 8,
                  &As[rb][0]);
      gload_lds16(bsrc + (size_t)(rb + (lane >> 3)) * L_DIM + k0 + (lane & 7) * 8,
                  &Bs[rb][0]);
    }
    __syncthreads();
#pragma unroll
    for (int kk = 0; kk < 64; kk += 32) {
      bf16x8 af[4], bfr[4];
#pragma unroll
      for (int m = 0; m < 4; ++m)
        af[m] = *(const bf16x8*)&As[wr * 64 + m * 16 + lrow][kk + lkb * 8];
#pragma unroll
      for (int n = 0; n < 4; ++n)
        bfr[n] = *(const bf16x8*)&Bs[wc * 64 + n * 16 + lrow][kk + lkb * 8];
#pragma unroll
      for (int m = 0; m < 4; ++m)
#pragma unroll
        for (int n = 0; n < 4; ++n)
          acc[m][n] = __builtin_amdgcn_mfma_f32_16x16x32_bf16(
              bfr[n], af[m], acc[m][n], 0, 0, 0);  // swapped operands
    }
    __syncthreads();
  }

  int q = wc * 4 + lkb;  // contributor index 0..7 per row
#pragma unroll
  for (int m = 0; m < 4; ++m) {
    int row_l = wr * 64 + m * 16 + lrow;
    float p[C_CLS] = {0.f, 0.f, 0.f, 0.f, 0.f};
#pragma unroll
    for (int n = 0; n < 4; ++n) {
      int d0 = wc * 64 + n * 16 + lkb * 4;
#pragma unroll
      for (int r = 0; r < 4; ++r) {
        float v = tanhf(acc[m][n][r] + bias[d0 + r]);
        const float* wrow = &aW2_l[(d0 + r) * C_CLS];
#pragma unroll
        for (int c = 0; c < C_CLS; ++c) p[c] = fmaf(v, wrow[c], p[c]);
      }
    }
#pragma unroll
    for (int c = 0; c < C_CLS; ++c) part[row_l][q][c] = p[c];
  }
  __syncthreads();

  if (tid < 128) {
    int gi = i0 + tid;
    float a[C_CLS];
#pragma unroll
    for (int c = 0; c < C_CLS; ++c) a[c] = ab2[c];
#pragma unroll
    for (int qq = 0; qq < 8; ++qq)
#pragma unroll
      for (int c = 0; c < C_CLS; ++c) a[c] += part[tid][qq][c];
#pragma unroll
    for (int c = 0; c < C_CLS; ++c) {
      float e = expf(a[c]);
      exp_att[(size_t)gi * C_CLS + c] = e;
      atomicAdd(&cs_l[c], e);
    }
  }
  __syncthreads();
  if (tid < C_CLS) atomicAdd(&colsum[tid], cs_l[tid]);
}

// ---- head: dist cols j in [0,27) via MFMA (the pre-window columns) -------
__global__ __launch_bounds__(256) void head_kernel(
    const unsigned short* __restrict__ xbf, const float* __restrict__ sqv,
    float* __restrict__ F) {
  int tid = threadIdx.x;
  int w = tid >> 6, lane = tid & 63;
  int lrow = lane & 15, lkb = lane >> 4;
  int rowb = blockIdx.x * 128 + w * 32;

  f32x4 acc[2][2];
#pragma unroll
  for (int m = 0; m < 2; ++m)
#pragma unroll
    for (int n = 0; n < 2; ++n) acc[m][n] = (f32x4){0.f, 0.f, 0.f, 0.f};

  for (int t = 0; t < 12; ++t) {
    bf16x8 af[2], bfr[2];
#pragma unroll
    for (int m = 0; m < 2; ++m)
      af[m] = *(const bf16x8*)(xbf + (size_t)(rowb + m * 16 + lrow) * L_DIM +
                               t * 32 + lkb * 8);
#pragma unroll
    for (int n = 0; n < 2; ++n)
      bfr[n] = *(const bf16x8*)(xbf + (size_t)(n * 16 + lrow) * L_DIM +
                                t * 32 + lkb * 8);
#pragma unroll
    for (int m = 0; m < 2; ++m)
#pragma unroll
      for (int n = 0; n < 2; ++n)
        acc[m][n] = __builtin_amdgcn_mfma_f32_16x16x32_bf16(
            bfr[n], af[m], acc[m][n], 0, 0, 0);  // swapped operands
  }

#pragma unroll
  for (int m = 0; m < 2; ++m) {
    int gi = rowb + m * 16 + lrow;
    float si = sqv[gi];
    float* orow = F + 5 + (size_t)gi * N_INST;
#pragma unroll
    for (int n = 0; n < 2; ++n) {
#pragma unroll
      for (int r = 0; r < 4; ++r) {
        int j = n * 16 + lkb * 4 + r;
        if (j < 27) {
          float d2 = si + sqv[j] - 2.f * acc[m][n][r];
          float dv = (d2 > 0.f) ? sqrtf(d2) : 0.f;
          if (gi == j) dv = 0.f;
          orow[j] = dv;
        }
      }
    }
  }
}

// ---- dist GEMM: 8-wave 128x256 tile, line-aligned windows ----------------
// dist[i][j] at F[5 + i*8192 + j]. 2048 blocks (64 ti x 32 tj), 512 thr =
// 8 waves (2 wave-rows x 4 wave-cols), each wave 64x64 out. vs the 4-wave
// 128x128 tile: half the blocks, half the barriers, 25% less staged bytes
// per output byte — attacks the per-block K-loop orchestration overhead
// (R1-R11: MfmaUtil 11%, VALUBusy 26%, Occ 40% — nothing saturated; all
// write-side fixes plateaued at ~187-191 us).
// Windows j = 27 + 256k (kept from R11: per-row 1KB segments = whole 128B
// lines, no cross-block line sharing); head covers j<27, tail masked.
// Inner loop: T2 XOR-swizzled LDS (48 KB), global_load_lds staging.
// acc[m][n][r]: i = i0+wr*64+m*16+lrow ; j = jbase+wc*64+n*16+lkb*4+r
__global__ __launch_bounds__(512, 2) void dist_kernel(
    const unsigned short* __restrict__ xbf, const float* __restrict__ sqv,
    float* __restrict__ F) {
  __shared__ alignas(16) unsigned short As[128][64];
  __shared__ alignas(16) unsigned short Bs[256][64];

  int tid = threadIdx.x;
  int wid = tid >> 6, lane = tid & 63;
  int wr = wid >> 2, wc = wid & 3;

  int b = blockIdx.x;
  int ti = b >> 5, tj = b & 31;
  int i0 = ti * 128;
  int jbase = tj * 256 + 27;

  const unsigned short* asrc = xbf + (size_t)i0 * L_DIM;
  const unsigned short* bsrc = xbf + (size_t)jbase * L_DIM;

  f32x4 acc[4][4];
#pragma unroll
  for (int m = 0; m < 4; ++m)
#pragma unroll
    for (int n = 0; n < 4; ++n) acc[m][n] = (f32x4){0.f, 0.f, 0.f, 0.f};

  int lrow = lane & 15, lkb = lane >> 4;
  int schunk = ((lane & 7) ^ (lane >> 3)) * 8;  // pre-swizzled source chunk
  int swz = (lane & 7) << 3;                    // read-side xor

  for (int kc = 0; kc < 6; ++kc) {
    int k0 = kc * 64;
    // A: 128 rows = 16 x 1KB chunks (8 rows each); 2 per wave
#pragma unroll
    for (int c = 0; c < 2; ++c) {
      int rb = c * 64 + wid * 8;
      gload_lds16(asrc + (size_t)(rb + (lane >> 3)) * L_DIM + k0 + schunk,
                  &As[rb][0]);
    }
    // B: 256 rows = 32 chunks; 4 per wave
#pragma unroll
    for (int c = 0; c < 4; ++c) {
      int rb = c * 64 + wid * 8;
      gload_lds16(bsrc + (size_t)(rb + (lane >> 3)) * L_DIM + k0 + schunk,
                  &Bs[rb][0]);
    }
    __syncthreads();
#pragma unroll
    for (int kk = 0; kk < 64; kk += 32) {
      bf16x8 af[4], bfr[4];
#pragma unroll
      for (int m = 0; m < 4; ++m)
        af[m] = *(const bf16x8*)&As[wr * 64 + m * 16 + lrow][(kk + lkb * 8) ^ swz];
#pragma unroll
      for (int n = 0; n < 4; ++n)
        bfr[n] = *(const bf16x8*)&Bs[wc * 64 + n * 16 + lrow][(kk + lkb * 8) ^ swz];
#pragma unroll
      for (int m = 0; m < 4; ++m)
#pragma unroll
        for (int n = 0; n < 4; ++n)
          acc[m][n] = __builtin_amdgcn_mfma_f32_16x16x32_bf16(
              bfr[n], af[m], acc[m][n], 0, 0, 0);  // swapped operands
    }
    __syncthreads();
  }

  // epilogue: 16B-aligned f32x4 stores; (5+gjb) % 4 == 0 since gjb%4 == 3
#pragma unroll
  for (int m = 0; m < 4; ++m) {
    int gi = i0 + wr * 64 + m * 16 + lrow;
    float si = sqv[gi];
    float* orow = F + 5 + (size_t)gi * N_INST;
#pragma unroll
    for (int n = 0; n < 4; ++n) {
      int gjb = jbase + wc * 64 + n * 16 + lkb * 4;
      f32x4u sj = *(const f32x4u*)&sqv[gjb];
      f32x4 o;
#pragma unroll
      for (int r = 0; r < 4; ++r) {
        float d2 = si + sj[r] - 2.f * acc[m][n][r];
        float dv = (d2 > 0.f) ? sqrtf(d2) : 0.f;
        if (gi == gjb + r) dv = 0.f;
        o[r] = dv;
      }
      if (gjb < N_INST - 4) {
        *(f32x4*)&orow[gjb] = o;        // aligned full vector
      } else if (gjb < N_INST) {
        orow[N_INST - 1] = o[0];        // gjb == 8191: single last column
      }                                  // gjb >= 8192: masked (tail window)
    }
  }
}

// ---- bagU[c][l] = sum_i exp_att[i][c] * x[i][l] --------------------------
__global__ __launch_bounds__(256) void bag_kernel(
    const float* __restrict__ x, const float* __restrict__ exp_att,
    float* __restrict__ bagU) {
  int t = threadIdx.x;
  int rbase = blockIdx.x * 32;
  float acc0[C_CLS] = {0, 0, 0, 0, 0}, acc1[C_CLS] = {0, 0, 0, 0, 0};
  int l0 = t, l1 = t + 256;  // l1 valid when t < 128
  for (int i = rbase; i < rbase + 32; ++i) {
    const float* xr = x + (size_t)i * L_DIM;
    float e[C_CLS];
#pragma unroll
    for (int c = 0; c < C_CLS; ++c) e[c] = exp_att[(size_t)i * C_CLS + c];
    float x0 = xr[l0];
#pragma unroll
    for (int c = 0; c < C_CLS; ++c) acc0[c] = fmaf(e[c], x0, acc0[c]);
    if (t < 128) {
      float x1 = xr[l1];
#pragma unroll
      for (int c = 0; c < C_CLS; ++c) acc1[c] = fmaf(e[c], x1, acc1[c]);
    }
  }
#pragma unroll
  for (int c = 0; c < C_CLS; ++c) atomicAdd(&bagU[c * L_DIM + l0], acc0[c]);
  if (t < 128)
#pragma unroll
    for (int c = 0; c < C_CLS; ++c) atomicAdd(&bagU[c * L_DIM + l1], acc1[c]);
}

// ---- final: normalize bag, per-class MLP head, write pred[0..4] ----------
__global__ __launch_bounds__(256) void final_kernel(
    const float* __restrict__ bagU, const float* __restrict__ colsum,
    const float* __restrict__ cW1, const float* __restrict__ cb1,
    const float* __restrict__ cW2, const float* __restrict__ cb2,
    float* __restrict__ out) {
  __shared__ float bag_s[C_CLS * L_DIM];
  __shared__ float h_s[C_CLS * 64];
  int t = threadIdx.x;
  for (int idx = t; idx < C_CLS * L_DIM; idx += 256) {
    int c = idx / L_DIM;
    bag_s[idx] = bagU[idx] / colsum[c];
  }
  __syncthreads();
  for (int idx = t; idx < C_CLS * 64; idx += 256) {
    int c = idx >> 6, hh = idx & 63;
    float acc = cb1[idx];
    for (int l = 0; l < L_DIM; ++l)
      acc = fmaf(bag_s[c * L_DIM + l], cW1[(size_t)(c * L_DIM + l) * 64 + hh], acc);
    h_s[idx] = fmaxf(acc, 0.f) * cW2[idx];
  }
  __syncthreads();
  if (t < C_CLS) {
    float p = cb2[t];
    for (int hh = 0; hh < 64; ++hh) p += h_s[t * 64 + hh];
    out[t] = p;
  }
}

extern "C" void kernel_launch(void* const* d_in, const int* in_sizes, int n_in,
                              void* d_out, int out_size, void* d_ws,
                              size_t ws_size, hipStream_t stream) {
  const float* x   = (const float*)d_in[0];
  const float* aW1 = (const float*)d_in[1];
  const float* ab1 = (const float*)d_in[2];
  const float* aW2 = (const float*)d_in[3];
  const float* ab2 = (const float*)d_in[4];
  const float* cW1 = (const float*)d_in[5];
  const float* cb1 = (const float*)d_in[6];
  const float* cW2 = (const float*)d_in[7];
  const float* cb2 = (const float*)d_in[8];
  float* outp = (float*)d_out;

  char* ws = (char*)d_ws;
  unsigned short* xbf = (unsigned short*)(ws);              // 6,291,456
  unsigned short* w1t = (unsigned short*)(ws + 6291456);    //    98,304
  float* sq           = (float*)(ws + 6389760);             //    32,768
  float* exp_att      = (float*)(ws + 6422528);             //   163,840
  float* colsum       = (float*)(ws + 6586368);             //        64
  float* bagU         = (float*)(ws + 6586432);             //     7,680

  hipMemsetAsync(ws + 6586368, 0, 64 + C_CLS * L_DIM * 4, stream);

  prep_x_kernel<<<2048, 256, 0, stream>>>(x, xbf, sq);
  prep_w_kernel<<<192, 256, 0, stream>>>(aW1, w1t);
  attn_gemm_kernel<<<64, 256, 0, stream>>>(xbf, w1t, ab1, aW2, ab2, exp_att,
                                           colsum);
  bag_kernel<<<256, 256, 0, stream>>>(x, exp_att, bagU);
  final_kernel<<<1, 256, 0, stream>>>(bagU, colsum, cW1, cb1, cW2, cb2, outp);
  head_kernel<<<64, 256, 0, stream>>>(xbf, sq, outp);
  dist_kernel<<<2048, 512, 0, stream>>>(xbf, sq, outp);
}